// Round 2
// baseline (708.090 us; speedup 1.0000x reference)
//
#include <hip/hip_runtime.h>

#define DD 160
#define HH 160
#define WW 160
#define S (DD*HH*WW)        // 4,096,000 voxels
#define NB 4000             // S / (256 threads * 4 voxels)
#define NB_PER (NB/8)       // blocks per XCD slab

__device__ __forceinline__ float fmul(float a, float b){ return __fmul_rn(a,b); }
__device__ __forceinline__ float fadd(float a, float b){ return __fadd_rn(a,b); }
__device__ __forceinline__ float fsub(float a, float b){ return __fsub_rn(a,b); }

// Round-robin XCD dispatch -> contiguous z-slab per XCD (L2 plane locality).
__device__ __forceinline__ int swz(int b){ return (b & 7) * NB_PER + (b >> 3); }

// ddf0 = (dvf0*(1-w) + dvf1*w) / 32, planar in -> interleaved out (xyz per voxel)
__global__ __launch_bounds__(256) void init_kernel(const float* __restrict__ dvf0,
                                                   const float* __restrict__ dvf1,
                                                   const float* __restrict__ wp,
                                                   float* __restrict__ outi) {
    int b = swz(blockIdx.x);
    int p = (b * 256 + threadIdx.x) * 4;
    float w = wp[0];
    float onew = fsub(1.0f, w);
    float a0[4], a1[4], a2[4], b0[4], b1[4], b2[4];
    *(float4*)a0 = *(const float4*)(dvf0 + p);
    *(float4*)a1 = *(const float4*)(dvf0 + S + p);
    *(float4*)a2 = *(const float4*)(dvf0 + 2 * S + p);
    *(float4*)b0 = *(const float4*)(dvf1 + p);
    *(float4*)b1 = *(const float4*)(dvf1 + S + p);
    *(float4*)b2 = *(const float4*)(dvf1 + 2 * S + p);
    float o[12];
    #pragma unroll
    for (int j = 0; j < 4; ++j) {
        o[3*j]   = fmul(fadd(fmul(a0[j], onew), fmul(b0[j], w)), 0.03125f);
        o[3*j+1] = fmul(fadd(fmul(a1[j], onew), fmul(b1[j], w)), 0.03125f);
        o[3*j+2] = fmul(fadd(fmul(a2[j], onew), fmul(b2[j], w)), 0.03125f);
    }
    float* dst = outi + (size_t)3 * p;
    *(float4*)(dst)     = *(float4*)(o);
    *(float4*)(dst + 4) = *(float4*)(o + 4);
    *(float4*)(dst + 8) = *(float4*)(o + 8);
}

// out = in + trilinear_warp(in, in). Interleaved input; PLANAR selects output layout.
template<bool PLANAR>
__global__ __launch_bounds__(256) void warp_step(const float* __restrict__ in,
                                                 float* __restrict__ out) {
    int b = swz(blockIdx.x);
    int p = (b * 256 + threadIdx.x) * 4;
    int x0 = p % WW;
    int r  = p / WW;
    int y  = r % HH;
    int z  = r / HH;

    float ctr[12];
    const float* src = in + (size_t)3 * p;
    *(float4*)(ctr)     = *(const float4*)(src);
    *(float4*)(ctr + 4) = *(const float4*)(src + 4);
    *(float4*)(ctr + 8) = *(const float4*)(src + 8);

    float res[12];
    #pragma unroll
    for (int j = 0; j < 4; ++j) {
        float vd = ctr[3*j], vh = ctr[3*j+1], vw = ctr[3*j+2];
        float cd = fadd((float)z, vd);
        float ch = fadd((float)y, vh);
        float cw = fadd((float)(x0 + j), vw);

        float d0 = floorf(cd), h0 = floorf(ch), w0 = floorf(cw);
        float fd = fsub(cd, d0), fh = fsub(ch, h0), fw = fsub(cw, w0);
        int d0i = (int)d0, h0i = (int)h0, w0i = (int)w0;

        float acc0 = 0.0f, acc1 = 0.0f, acc2 = 0.0f;
        #pragma unroll
        for (int dd = 0; dd < 2; ++dd) {
            #pragma unroll
            for (int dh = 0; dh < 2; ++dh) {
                #pragma unroll
                for (int dw = 0; dw < 2; ++dw) {
                    int di = d0i + dd, hi = h0i + dh, wi = w0i + dw;
                    bool valid = (di >= 0) & (di < DD) & (hi >= 0) & (hi < HH)
                               & (wi >= 0) & (wi < WW);
                    float wd  = dd ? fd : fsub(1.0f, fd);
                    float wh  = dh ? fh : fsub(1.0f, fh);
                    float ww_ = dw ? fw : fsub(1.0f, fw);
                    float wgt = fmul(fmul(wd, wh), ww_);
                    int dc = min(max(di, 0), DD - 1);
                    int hc = min(max(hi, 0), HH - 1);
                    int wc = min(max(wi, 0), WW - 1);
                    size_t q3 = (size_t)3 * ((dc * HH + hc) * WW + wc);
                    float g0 = in[q3], g1 = in[q3 + 1], g2 = in[q3 + 2];
                    float v0 = valid ? g0 : 0.0f;
                    float v1 = valid ? g1 : 0.0f;
                    float v2 = valid ? g2 : 0.0f;
                    acc0 = fadd(acc0, fmul(v0, wgt));
                    acc1 = fadd(acc1, fmul(v1, wgt));
                    acc2 = fadd(acc2, fmul(v2, wgt));
                }
            }
        }
        res[3*j]   = fadd(vd, acc0);
        res[3*j+1] = fadd(vh, acc1);
        res[3*j+2] = fadd(vw, acc2);
    }

    if (PLANAR) {
        float od[4], oh[4], ow[4];
        #pragma unroll
        for (int j = 0; j < 4; ++j) { od[j] = res[3*j]; oh[j] = res[3*j+1]; ow[j] = res[3*j+2]; }
        *(float4*)(out + p)         = *(float4*)od;
        *(float4*)(out + S + p)     = *(float4*)oh;
        *(float4*)(out + 2 * S + p) = *(float4*)ow;
    } else {
        float* dst = out + (size_t)3 * p;
        *(float4*)(dst)     = *(float4*)(res);
        *(float4*)(dst + 4) = *(float4*)(res + 4);
        *(float4*)(dst + 8) = *(float4*)(res + 8);
    }
}

// img trilinear + cav/cor nearest warp with final (planar) ddf.
__global__ __launch_bounds__(256) void final_kernel(const float* __restrict__ ddf,
                                                    const float* __restrict__ image,
                                                    const int* __restrict__ cav,
                                                    const int* __restrict__ cor,
                                                    float* __restrict__ out) {
    int b = swz(blockIdx.x);
    int p = (b * 256 + threadIdx.x) * 4;
    int x0 = p % WW;
    int r  = p / WW;
    int y  = r % HH;
    int z  = r / HH;

    float dzs[4], dhs[4], dws[4];
    *(float4*)dzs = *(const float4*)(ddf + p);
    *(float4*)dhs = *(const float4*)(ddf + S + p);
    *(float4*)dws = *(const float4*)(ddf + 2 * S + p);

    float oimg[4], ocav[4], ocor[4];
    #pragma unroll
    for (int j = 0; j < 4; ++j) {
        float cd = fadd((float)z, dzs[j]);
        float ch = fadd((float)y, dhs[j]);
        float cw = fadd((float)(x0 + j), dws[j]);

        float d0 = floorf(cd), h0 = floorf(ch), w0 = floorf(cw);
        float fd = fsub(cd, d0), fh = fsub(ch, h0), fw = fsub(cw, w0);
        int d0i = (int)d0, h0i = (int)h0, w0i = (int)w0;
        float acc = 0.0f;
        #pragma unroll
        for (int dd = 0; dd < 2; ++dd) {
            #pragma unroll
            for (int dh = 0; dh < 2; ++dh) {
                #pragma unroll
                for (int dw = 0; dw < 2; ++dw) {
                    int di = d0i + dd, hi = h0i + dh, wi = w0i + dw;
                    bool valid = (di >= 0) & (di < DD) & (hi >= 0) & (hi < HH)
                               & (wi >= 0) & (wi < WW);
                    float wd  = dd ? fd : fsub(1.0f, fd);
                    float wh  = dh ? fh : fsub(1.0f, fh);
                    float ww_ = dw ? fw : fsub(1.0f, fw);
                    float wgt = fmul(fmul(wd, wh), ww_);
                    int dc = min(max(di, 0), DD - 1);
                    int hc = min(max(hi, 0), HH - 1);
                    int wc = min(max(wi, 0), WW - 1);
                    int q = (dc * HH + hc) * WW + wc;
                    float v = valid ? image[q] : 0.0f;
                    acc = fadd(acc, fmul(v, wgt));
                }
            }
        }
        oimg[j] = acc;

        int di = (int)rintf(cd), hi = (int)rintf(ch), wi = (int)rintf(cw);
        bool valid = (di >= 0) & (di < DD) & (hi >= 0) & (hi < HH)
                   & (wi >= 0) & (wi < WW);
        int dc = min(max(di, 0), DD - 1);
        int hc = min(max(hi, 0), HH - 1);
        int wc = min(max(wi, 0), WW - 1);
        int q = (dc * HH + hc) * WW + wc;
        ocav[j] = valid ? (float)cav[q] : 0.0f;
        ocor[j] = valid ? (float)cor[q] : 0.0f;
    }
    *(float4*)(out + p)         = *(float4*)oimg;
    *(float4*)(out + S + p)     = *(float4*)ocav;
    *(float4*)(out + 2 * S + p) = *(float4*)ocor;
}

extern "C" void kernel_launch(void* const* d_in, const int* in_sizes, int n_in,
                              void* d_out, int out_size, void* d_ws, size_t ws_size,
                              hipStream_t stream) {
    const float* dvf0   = (const float*)d_in[0];
    const float* dvf1   = (const float*)d_in[1];
    const float* image  = (const float*)d_in[2];
    const int*   cav    = (const int*)d_in[3];
    const int*   cor    = (const int*)d_in[4];
    const float* w      = (const float*)d_in[5];

    float* out  = (float*)d_out;
    float* bufA = out;                    // interleaved scratch; img/cav/cor at the end
    float* bufB = out + (size_t)3 * S;    // interleaved scratch; final planar ddf

    init_kernel<<<NB, 256, 0, stream>>>(dvf0, dvf1, w, bufA);
    warp_step<false><<<NB, 256, 0, stream>>>(bufA, bufB);   // s1: A -> B
    warp_step<false><<<NB, 256, 0, stream>>>(bufB, bufA);   // s2: B -> A
    warp_step<false><<<NB, 256, 0, stream>>>(bufA, bufB);   // s3: A -> B
    warp_step<false><<<NB, 256, 0, stream>>>(bufB, bufA);   // s4: B -> A
    warp_step<true ><<<NB, 256, 0, stream>>>(bufA, bufB);   // s5: A -> B (planar ddf)
    final_kernel<<<NB, 256, 0, stream>>>(bufB, image, cav, cor, bufA);
}

// Round 3
// 593.234 us; speedup vs baseline: 1.1936x; 1.1936x over previous
//
#include <hip/hip_runtime.h>

#define DD 160
#define HH 160
#define WW 160
#define S (DD*HH*WW)     // 4,096,000 voxels

// warp_step/final grid: 32x8x1 tiles -> 5 x 20 x 160 = 16000 blocks
#define NB 16000
#define NB_PER (NB/8)    // 2000 blocks (20 z-planes) per XCD slab

__device__ __forceinline__ float fmul(float a, float b){ return __fmul_rn(a,b); }
__device__ __forceinline__ float fadd(float a, float b){ return __fadd_rn(a,b); }
__device__ __forceinline__ float fsub(float a, float b){ return __fsub_rn(a,b); }

// Round-robin XCD dispatch -> contiguous 20-z-plane slab per XCD (L2 locality).
__device__ __forceinline__ int swz(int b){ return (b & 7) * NB_PER + (b >> 3); }

// Block tile 32(x) x 8(y) x 1(z); wave footprint = 32x2 patch (compact gathers).
__device__ __forceinline__ void tile_coords(int blk, int tid, int& x, int& y, int& z) {
    int b  = swz(blk);
    int ix = b % 5;
    int iy = (b / 5) % 20;
    int iz = b / 100;
    int lane = tid & 63, wid = tid >> 6;
    x = (ix << 5) | (lane & 31);
    y = (iy << 3) | (wid << 1) | (lane >> 5);
    z = iz;
}

// ddf0 = (dvf0*(1-w) + dvf1*w) / 32  -- bit-exact replica of reference order
__global__ __launch_bounds__(256) void init_kernel(const float* __restrict__ dvf0,
                                                   const float* __restrict__ dvf1,
                                                   const float* __restrict__ wp,
                                                   float* __restrict__ out) {
    int i = (blockIdx.x * 256 + threadIdx.x) * 4;   // 12000 blocks cover 3S exactly
    float w = wp[0];
    float onew = fsub(1.0f, w);
    float a[4], b[4], o[4];
    *(float4*)a = *(const float4*)(dvf0 + i);
    *(float4*)b = *(const float4*)(dvf1 + i);
    #pragma unroll
    for (int j = 0; j < 4; ++j)
        o[j] = fmul(fadd(fmul(a[j], onew), fmul(b[j], w)), 0.03125f);
    *(float4*)(out + i) = *(float4*)o;
}

// out = in + trilinear_warp(in, in). Planar layout, scalar taps, compact waves.
__global__ __launch_bounds__(256) void warp_step(const float* __restrict__ in,
                                                 float* __restrict__ out) {
    int x, y, z;
    tile_coords(blockIdx.x, threadIdx.x, x, y, z);
    int p = (z * HH + y) * WW + x;

    float vd = in[p];
    float vh = in[S + p];
    float vw = in[2 * S + p];

    float cd = fadd((float)z, vd);
    float ch = fadd((float)y, vh);
    float cw = fadd((float)x, vw);

    float d0 = floorf(cd), h0 = floorf(ch), w0 = floorf(cw);
    float fd = fsub(cd, d0), fh = fsub(ch, h0), fw = fsub(cw, w0);
    int d0i = (int)d0, h0i = (int)h0, w0i = (int)w0;

    float acc0 = 0.0f, acc1 = 0.0f, acc2 = 0.0f;
    #pragma unroll
    for (int dd = 0; dd < 2; ++dd) {
        #pragma unroll
        for (int dh = 0; dh < 2; ++dh) {
            #pragma unroll
            for (int dw = 0; dw < 2; ++dw) {
                int di = d0i + dd, hi = h0i + dh, wi = w0i + dw;
                bool valid = (di >= 0) & (di < DD) & (hi >= 0) & (hi < HH)
                           & (wi >= 0) & (wi < WW);
                float wd  = dd ? fd : fsub(1.0f, fd);
                float wh  = dh ? fh : fsub(1.0f, fh);
                float ww_ = dw ? fw : fsub(1.0f, fw);
                float wgt = fmul(fmul(wd, wh), ww_);
                int dc = min(max(di, 0), DD - 1);
                int hc = min(max(hi, 0), HH - 1);
                int wc = min(max(wi, 0), WW - 1);
                int q = (dc * HH + hc) * WW + wc;
                float v0 = valid ? in[q]         : 0.0f;
                float v1 = valid ? in[S + q]     : 0.0f;
                float v2 = valid ? in[2 * S + q] : 0.0f;
                acc0 = fadd(acc0, fmul(v0, wgt));
                acc1 = fadd(acc1, fmul(v1, wgt));
                acc2 = fadd(acc2, fmul(v2, wgt));
            }
        }
    }
    out[p]         = fadd(vd, acc0);
    out[S + p]     = fadd(vh, acc1);
    out[2 * S + p] = fadd(vw, acc2);
}

// img trilinear + cav/cor nearest warp with final (planar) ddf.
// out layout: [0,S) img, [S,2S) cav, [2S,3S) cor (all as float)
__global__ __launch_bounds__(256) void final_kernel(const float* __restrict__ ddf,
                                                    const float* __restrict__ image,
                                                    const int* __restrict__ cav,
                                                    const int* __restrict__ cor,
                                                    float* __restrict__ out) {
    int x, y, z;
    tile_coords(blockIdx.x, threadIdx.x, x, y, z);
    int p = (z * HH + y) * WW + x;

    float cd = fadd((float)z, ddf[p]);
    float ch = fadd((float)y, ddf[S + p]);
    float cw = fadd((float)x, ddf[2 * S + p]);

    float d0 = floorf(cd), h0 = floorf(ch), w0 = floorf(cw);
    float fd = fsub(cd, d0), fh = fsub(ch, h0), fw = fsub(cw, w0);
    int d0i = (int)d0, h0i = (int)h0, w0i = (int)w0;
    float acc = 0.0f;
    #pragma unroll
    for (int dd = 0; dd < 2; ++dd) {
        #pragma unroll
        for (int dh = 0; dh < 2; ++dh) {
            #pragma unroll
            for (int dw = 0; dw < 2; ++dw) {
                int di = d0i + dd, hi = h0i + dh, wi = w0i + dw;
                bool valid = (di >= 0) & (di < DD) & (hi >= 0) & (hi < HH)
                           & (wi >= 0) & (wi < WW);
                float wd  = dd ? fd : fsub(1.0f, fd);
                float wh  = dh ? fh : fsub(1.0f, fh);
                float ww_ = dw ? fw : fsub(1.0f, fw);
                float wgt = fmul(fmul(wd, wh), ww_);
                int dc = min(max(di, 0), DD - 1);
                int hc = min(max(hi, 0), HH - 1);
                int wc = min(max(wi, 0), WW - 1);
                int q = (dc * HH + hc) * WW + wc;
                float v = valid ? image[q] : 0.0f;
                acc = fadd(acc, fmul(v, wgt));
            }
        }
    }
    out[p] = acc;

    // nearest labels (round half to even, matches jnp.round)
    int di = (int)rintf(cd), hi = (int)rintf(ch), wi = (int)rintf(cw);
    bool valid = (di >= 0) & (di < DD) & (hi >= 0) & (hi < HH)
               & (wi >= 0) & (wi < WW);
    int dc = min(max(di, 0), DD - 1);
    int hc = min(max(hi, 0), HH - 1);
    int wc = min(max(wi, 0), WW - 1);
    int q = (dc * HH + hc) * WW + wc;
    out[S + p]     = valid ? (float)cav[q] : 0.0f;
    out[2 * S + p] = valid ? (float)cor[q] : 0.0f;
}

extern "C" void kernel_launch(void* const* d_in, const int* in_sizes, int n_in,
                              void* d_out, int out_size, void* d_ws, size_t ws_size,
                              hipStream_t stream) {
    const float* dvf0   = (const float*)d_in[0];
    const float* dvf1   = (const float*)d_in[1];
    const float* image  = (const float*)d_in[2];
    const int*   cav    = (const int*)d_in[3];
    const int*   cor    = (const int*)d_in[4];
    const float* w      = (const float*)d_in[5];

    float* out  = (float*)d_out;
    float* bufA = out;                    // scratch now; img/cav/cor at the end
    float* bufB = out + (size_t)3 * S;    // final planar ddf lives here

    init_kernel<<<12000, 256, 0, stream>>>(dvf0, dvf1, w, bufA);
    warp_step<<<NB, 256, 0, stream>>>(bufA, bufB);   // s1
    warp_step<<<NB, 256, 0, stream>>>(bufB, bufA);   // s2
    warp_step<<<NB, 256, 0, stream>>>(bufA, bufB);   // s3
    warp_step<<<NB, 256, 0, stream>>>(bufB, bufA);   // s4
    warp_step<<<NB, 256, 0, stream>>>(bufA, bufB);   // s5 -> final ddf in bufB
    final_kernel<<<NB, 256, 0, stream>>>(bufB, image, cav, cor, bufA);
}